// Round 10
// baseline (67.515 us; speedup 1.0000x reference)
//
#include <hip/hip_runtime.h>

#define NSC 64      // Ns
#define NWN 12      // nw
#define LWN 6       // lw
#define NZD 200     // Nz
#define NFRAMES 6
#define NL 4        // cells per lane
#define ACTL 50     // active lanes (50*4 = 200)

typedef float v2f __attribute__((ext_vector_type(2)));

__device__ __forceinline__ float frcp(float x) { return __builtin_amdgcn_rcpf(x); }
__device__ __forceinline__ float frsq(float x) { return __builtin_amdgcn_rsqf(x); }
#if __has_builtin(__builtin_amdgcn_exp2f)
__device__ __forceinline__ float fexp2(float x) { return __builtin_amdgcn_exp2f(x); }
#else
__device__ __forceinline__ float fexp2(float x) { return exp2f(x); }
#endif

__device__ __forceinline__ v2f v2s(float s)            { v2f r; r.x = s;  r.y = s;  return r; }
__device__ __forceinline__ v2f v2mk(float a, float b)  { v2f r; r.x = a;  r.y = b;  return r; }
__device__ __forceinline__ v2f v2rcp(v2f x)  { return v2mk(frcp(x.x),  frcp(x.y)); }
__device__ __forceinline__ v2f v2rsq(v2f x)  { return v2mk(frsq(x.x),  frsq(x.y)); }
__device__ __forceinline__ v2f v2exp2(v2f x) { return v2mk(fexp2(x.x), fexp2(x.y)); }
__device__ __forceinline__ v2f v2abs(v2f x)  { return v2mk(fabsf(x.x), fabsf(x.y)); }

// DPP lane-shift moves (bound_ctrl -> 0 at edges).
// wave_shr1 (0x138): lane i reads lane i-1 ; wave_shl1 (0x130): lane i reads lane i+1
template<int CTRL>
__device__ __forceinline__ float dppmov(float x) {
    return __int_as_float(__builtin_amdgcn_update_dpp(0, __float_as_int(x), CTRL, 0xf, 0xf, true));
}
template<int CTRL>
__device__ __forceinline__ v2f dppmov2(v2f x) { return v2mk(dppmov<CTRL>(x.x), dppmov<CTRL>(x.y)); }
__device__ __forceinline__ v2f nbr_p1(v2f x) { return dppmov2<0x130>(x); }  // from lane+1
__device__ __forceinline__ v2f nbr_m1(v2f x) { return dppmov2<0x138>(x); }  // from lane-1
__device__ __forceinline__ v2f nbr_p2(v2f x) { return nbr_p1(nbr_p1(x)); }
__device__ __forceinline__ v2f nbr_m2(v2f x) { return nbr_m1(nbr_m1(x)); }

template<int CTRL, int RMASK, bool BC>
__device__ __forceinline__ float dppadd(float x) {
    const int t = __builtin_amdgcn_update_dpp(0, __float_as_int(x), CTRL, RMASK, 0xf, BC);
    return x + __int_as_float(t);
}
__device__ __forceinline__ float wave_iscan(float x) {
    x = dppadd<0x111, 0xf, true>(x);
    x = dppadd<0x112, 0xf, true>(x);
    x = dppadd<0x114, 0xf, true>(x);
    x = dppadd<0x118, 0xf, true>(x);
    x = dppadd<0x142, 0xa, false>(x);
    x = dppadd<0x143, 0xc, false>(x);
    return x;
}
__device__ __forceinline__ v2f wave_iscan2(v2f x) { return v2mk(wave_iscan(x.x), wave_iscan(x.y)); }

// WENO3-Z with precomputed smoothness b1,b2 and single reciprocal (per component).
__device__ __forceinline__ v2f weno3z_v(v2f qm, v2f q0, v2f qp, v2f b1, v2f b2) {
    const v2f qi1 = 1.5f * q0 - 0.5f * qm;
    const v2f qi2 = 0.5f * (q0 + qp);
    const v2f b1e = b1 + 1e-14f;
    const v2f b2e = b2 + 1e-14f;
    const v2f tau = v2abs(b2 - b1);
    const v2f W1 = (b1e + tau) * b2e;
    const v2f W2 = 2.f * (b2e + tau) * b1e;
    return (W1 * qi1 + W2 * qi2) * v2rcp(W1 + W2);
}

__global__ __launch_bounds__(64, 1) void nnpzd_wave(
    const float* __restrict__ Kz, const float* __restrict__ I0,
    const float* __restrict__ alpha_p, const float* __restrict__ Xi_p,
    const float* __restrict__ rho_p, const float* __restrict__ gamma_p,
    const float* __restrict__ Gamma_p, const float* __restrict__ varphi_p,
    const float* __restrict__ omega_p, const float* __restrict__ beta_p,
    const float* __restrict__ NO3_0, const float* __restrict__ NH4_0,
    const float* __restrict__ P_0, const float* __restrict__ Z_0,
    const float* __restrict__ D_0, const float* __restrict__ subw,
    const float* __restrict__ zT, const float* __restrict__ zw,
    float* __restrict__ out)
{
    const float XI = 0.067f, ZETA = 0.0095f, LAM = 0.06f, PSI = 1.46f;
    const float MU = 0.25f, ETA = 1.5f, KAP = 1.0f, DT = 0.125f;
    const float LOG2E = 1.44269504088896340736f;
    const float ZL2 = -ZETA * LOG2E;
    const float PL2 = -PSI * LOG2E;
    const float LL2 = -LAM * LOG2E;

    const int col0 = blockIdx.x * 2;        // two adjacent windows, same scenario
    const int si   = col0 / NWN;
    const int wi0  = col0 - si * NWN;       // even; wi0+1 <= 11
    const int lane = threadIdx.x;
    const bool act = lane < ACTL;
    const int  c0  = lane * NL;

    const float pa   = alpha_p[si];
    const float pXi  = Xi_p[si];
    const float prho = rho_p[si];
    const float pgam = gamma_p[si];
    const float pGam = Gamma_p[si];
    const float pvar = varphi_p[si];
    const float sedc = omega_p[si];
    const float pbet = beta_p[si];
    const int sw0a = (int)subw[wi0 * LWN];
    const int sw0b = (int)subw[(wi0 + 1) * LWN];

    // ---- per-lane constant geometry (scalar, shared by both columns) ----
    float dzT[NL], DTdz[NL], ezT[NL], kAf[NL], kCf[NL], swN[NL], swN4;
    {
        float dzw_[NL + 2];
        #pragma unroll
        for (int j = 0; j <= NL + 1; ++j) {
            const int i = act ? (c0 + j) : 0;
            dzw_[j] = (i == 0)   ? 0.5f * (zw[1] - zw[0])
                    : (i >= NZD) ? 0.5f * (zw[NZD] - zw[NZD - 1])
                                 : (zT[i] - zT[i - 1]);
        }
        #pragma unroll
        for (int j = 0; j < NL; ++j) {
            const int i = act ? (c0 + j) : 0;
            const float dz = zw[i + 1] - zw[i];
            dzT[j]  = dz;
            DTdz[j] = act ? (DT / dz) : 0.f;
            ezT[j]  = expf(-XI * zT[i]);
            kAf[j]  = (act && (c0 + j) >= 1)       ? (-DT / (dz * dzw_[j]))     : 0.f;
            kCf[j]  = (act && (c0 + j) <= NZD - 2) ? (-DT / (dz * dzw_[j + 1])) : 0.f;
            swN[j]  = act ? (sedc / dzw_[j]) : 0.f;
        }
        swN4 = act ? (sedc / dzw_[NL]) : 0.f;
    }

    // ---- initial state: two float4 loads per tracer, packed into v2f ----
    v2f vN[NL], vA[NL], vP[NL], vZ[NL], vD[NL];
    {
        const size_t ib0 = (size_t)col0 * NZD + c0;
        const size_t ib1 = ib0 + NZD;
        if (act) {
            const float4 nx = *reinterpret_cast<const float4*>(&NO3_0[ib0]);
            const float4 ny = *reinterpret_cast<const float4*>(&NO3_0[ib1]);
            const float4 ax = *reinterpret_cast<const float4*>(&NH4_0[ib0]);
            const float4 ay = *reinterpret_cast<const float4*>(&NH4_0[ib1]);
            const float4 px = *reinterpret_cast<const float4*>(&P_0[ib0]);
            const float4 py = *reinterpret_cast<const float4*>(&P_0[ib1]);
            const float4 zx = *reinterpret_cast<const float4*>(&Z_0[ib0]);
            const float4 zy = *reinterpret_cast<const float4*>(&Z_0[ib1]);
            const float4 dx = *reinterpret_cast<const float4*>(&D_0[ib0]);
            const float4 dy = *reinterpret_cast<const float4*>(&D_0[ib1]);
            vN[0]=v2mk(nx.x,ny.x); vN[1]=v2mk(nx.y,ny.y); vN[2]=v2mk(nx.z,ny.z); vN[3]=v2mk(nx.w,ny.w);
            vA[0]=v2mk(ax.x,ay.x); vA[1]=v2mk(ax.y,ay.y); vA[2]=v2mk(ax.z,ay.z); vA[3]=v2mk(ax.w,ay.w);
            vP[0]=v2mk(px.x,py.x); vP[1]=v2mk(px.y,py.y); vP[2]=v2mk(px.z,py.z); vP[3]=v2mk(px.w,py.w);
            vZ[0]=v2mk(zx.x,zy.x); vZ[1]=v2mk(zx.y,zy.y); vZ[2]=v2mk(zx.z,zy.z); vZ[3]=v2mk(zx.w,zy.w);
            vD[0]=v2mk(dx.x,dy.x); vD[1]=v2mk(dx.y,dy.y); vD[2]=v2mk(dx.z,dy.z); vD[3]=v2mk(dx.w,dy.w);
        } else {
            #pragma unroll
            for (int j = 0; j < NL; ++j) { vN[j]=vA[j]=vP[j]=vZ[j]=vD[j]=v2s(0.f); }
        }
    }

    const size_t ob0base = (size_t)col0 * (NFRAMES * 5 * NZD);
    const size_t ob1base = ob0base + (size_t)(NFRAMES * 5 * NZD);
    // frame 0
    if (act) {
        #define WRFRAME(base, comp)                                                                   \
            *reinterpret_cast<float4*>(&out[(base) + 0 * NZD + c0]) = make_float4(vN[0].comp,vN[1].comp,vN[2].comp,vN[3].comp); \
            *reinterpret_cast<float4*>(&out[(base) + 1 * NZD + c0]) = make_float4(vA[0].comp,vA[1].comp,vA[2].comp,vA[3].comp); \
            *reinterpret_cast<float4*>(&out[(base) + 2 * NZD + c0]) = make_float4(vP[0].comp,vP[1].comp,vP[2].comp,vP[3].comp); \
            *reinterpret_cast<float4*>(&out[(base) + 3 * NZD + c0]) = make_float4(vZ[0].comp,vZ[1].comp,vZ[2].comp,vZ[3].comp); \
            *reinterpret_cast<float4*>(&out[(base) + 4 * NZD + c0]) = make_float4(vD[0].comp,vD[1].comp,vD[2].comp,vD[3].comp);
        WRFRAME(ob0base, x)
        WRFRAME(ob1base, y)
    }

    const float* KzBase = Kz + (size_t)si * (2 * NWN * LWN + 2) * (NZD + 1);
    const float* I0row  = I0 + (size_t)si * (NWN * LWN + 1);

    // ---- factors rebuilt every 4 steps (v2f: per column) ----
    v2f t00, t10, t11, t20, t21, t22, t30, t31, t32, t33;
    v2f ecf0, ecf1, ecf2;
    v2f aa0, aa1, aa2, cl0, cl1, cl2, cl3;
    v2f E1a, E2a, E1b, E2b, invbF;
    v2f Iez[NL];

    // prefetch first Kz rows
    v2f kzc[NL + 1];
    {
        const float* k0 = KzBase + (size_t)(2 * sw0a) * (NZD + 1);
        const float* k1 = KzBase + (size_t)(2 * sw0b) * (NZD + 1);
        #pragma unroll
        for (int j = 0; j <= NL; ++j) kzc[j] = act ? v2mk(k0[c0 + j], k1[c0 + j]) : v2s(0.f);
    }
    v2f curI0 = v2mk(I0row[sw0a], I0row[sw0b]);
    v2f curSw = v2mk(subw[wi0 * LWN + 1], subw[(wi0 + 1) * LWN + 1]);
    v2f nxtI0 = v2s(0.f), nxtSw = v2s(0.f);

    // per-tracer implicit solve (DPP-only cross-lane; factors captured)
    auto solve = [&](const v2f* d, v2f* Xo) {
        const v2f Ec  = ecf0 * d[0] + ecf1 * d[1] + ecf2 * d[2];
        const v2f En  = nbr_p1(Ec);
        const v2f Dt3 = t30 * d[0] + t31 * d[1] + t32 * d[2] + t33 * d[3];
        v2f dR = Dt3 - cl3 * En;
        dR += E1a * nbr_m1(dR) + E2a * nbr_p1(dR);
        dR += E1b * nbr_m2(dR) + E2b * nbr_p2(dR);
        const v2f y  = dR * invbF;
        const v2f xm = nbr_m1(y);
        const v2f Dt0 = t00 * d[0];
        const v2f Dt1 = t10 * d[0] + t11 * d[1];
        const v2f Dt2 = t20 * d[0] + t21 * d[1] + t22 * d[2];
        Xo[3] = y;
        Xo[2] = Dt2 - aa2 * xm - cl2 * Xo[3];
        Xo[1] = Dt1 - aa1 * xm - cl1 * Xo[2];
        Xo[0] = Dt0 - aa0 * xm - cl0 * Xo[1];
    };

    for (int d8 = 0; d8 < 5; ++d8) {
        if (d8 < 4) {
            nxtI0 = v2mk(I0row[sw0a + d8 + 1], I0row[sw0b + d8 + 1]);
            nxtSw = v2mk(subw[wi0 * LWN + d8 + 2], subw[(wi0 + 1) * LWN + d8 + 2]);
        }
        #pragma unroll
        for (int j = 0; j < NL; ++j) Iez[j] = curI0 * ezT[j];
        v2f rap;
        rap.x = 0.05f * (fminf(fmaxf(curSw.x - 30.f, 0.f), 1.f) - fminf(fmaxf(curSw.x - 60.f, 0.f), 1.f));
        rap.y = 0.05f * (fminf(fmaxf(curSw.y - 30.f, 0.f), 1.f) - fminf(fmaxf(curSw.y - 60.f, 0.f), 1.f));

        for (int k4 = 0; k4 < 2; ++k4) {
            // ---- rebuild matrix factors from prefetched Kz ----
            v2f ac_[NL], cc_[NL];
            #pragma unroll
            for (int j = 0; j < NL; ++j) {
                ac_[j] = kAf[j] * kzc[j];
                cc_[j] = kCf[j] * kzc[j + 1];
            }
            {   // prefetch next Kz rows (row = 2*sw0 + 2*d8 + k4 + 1, in-bounds)
                const int r = 2 * d8 + k4 + 1;
                const float* k0 = KzBase + (size_t)(2 * sw0a + r) * (NZD + 1);
                const float* k1 = KzBase + (size_t)(2 * sw0b + r) * (NZD + 1);
                #pragma unroll
                for (int j = 0; j <= NL; ++j) kzc[j] = act ? v2mk(k0[c0 + j], k1[c0 + j]) : v2s(0.f);
            }
            const v2f iv0 = v2rcp(1.f - ac_[0] - cc_[0]);
            cl0 = cc_[0] * iv0;
            aa0 = ac_[0] * iv0;
            t00 = iv0;
            const v2f iv1 = v2rcp(1.f - ac_[1] - cc_[1] - ac_[1] * cl0);
            const v2f qf1 = ac_[1] * iv1;
            cl1 = cc_[1] * iv1;
            aa1 = -qf1 * aa0;
            t11 = iv1; t10 = -qf1 * t00;
            const v2f iv2 = v2rcp(1.f - ac_[2] - cc_[2] - ac_[2] * cl1);
            const v2f qf2 = ac_[2] * iv2;
            cl2 = cc_[2] * iv2;
            aa2 = -qf2 * aa1;
            t22 = iv2; t21 = -qf2 * t11; t20 = -qf2 * t10;
            const v2f iv3 = v2rcp(1.f - ac_[3] - cc_[3] - ac_[3] * cl2);
            const v2f qf3 = ac_[3] * iv3;
            cl3 = cc_[3] * iv3;
            const v2f aa3 = -qf3 * aa2;
            t33 = iv3; t32 = -qf3 * t22; t31 = -qf3 * t21; t30 = -qf3 * t20;
            const v2f c01 = cl0 * cl1;
            ecf0 = t00 - cl0 * t10 + c01 * t20;
            ecf1 = -cl0 * t11 + c01 * t21;
            ecf2 = c01 * t22;
            const v2f F = aa0 - cl0 * (aa1 - cl1 * aa2);
            const v2f G = cl0 * cl1 * cl2;
            const v2f Fn = nbr_p1(F);
            const v2f Gn = nbr_p1(G);
            v2f aR = aa3;
            v2f bR = 1.f - cl3 * Fn;
            v2f cR = -cl3 * Gn;
            if (!act) { aR = v2s(0.f); bR = v2s(1.f); cR = v2s(0.f); }
            const v2f ib  = v2rcp(bR);
            const v2f am  = nbr_m1(aR), ibm = nbr_m1(ib), cm = nbr_m1(cR);
            const v2f ap  = nbr_p1(aR), ibp = nbr_p1(ib), cp = nbr_p1(cR);
            E1a = -aR * ibm;
            E2a = -cR * ibp;
            const v2f b1r = bR + E1a * cm + E2a * ap;
            const v2f a1r = E1a * am;
            const v2f c1r = E2a * cp;
            const v2f ib1  = v2rcp(b1r);
            const v2f am2  = nbr_m2(a1r), ib1m = nbr_m2(ib1), cm2 = nbr_m2(c1r);
            const v2f ap2  = nbr_p2(a1r), ib1p = nbr_p2(ib1), cp2 = nbr_p2(c1r);
            E1b = -a1r * ib1m;
            E2b = -c1r * ib1p;
            invbF = v2rcp(b1r + E1b * cm2 + E2b * ap2);

            #pragma unroll
            for (int k2 = 0; k2 < 4; ++k2) {
                // ---- cumsum of P*dzT ----
                v2f cl_[NL];
                v2f run = v2s(0.f);
                #pragma unroll
                for (int j = 0; j < NL; ++j) { run += vP[j] * dzT[j]; cl_[j] = run; }
                const v2f pref = wave_iscan2(run) - run;

                // ---- It-independent tendencies (Z, D) ----
                v2f grz[NL], ddZ[NL], ddD[NL];
                #pragma unroll
                for (int j = 0; j < NL; ++j) {
                    grz[j] = prho * (1.f - v2exp2(LL2 * vP[j])) * vZ[j];
                    ddZ[j] = vZ[j] + DT * ((1.f - pgam) * grz[j] - pGam * vZ[j]);
                    ddD[j] = vD[j] + DT * (pgam * grz[j] + pXi * vP[j] - pvar * vD[j]);
                }
                v2f XD[NL];
                solve(ddD, XD);        // D first: feeds the long WENO chain

                // ---- It-dependent tendencies ----
                v2f dd0[NL], dd1[NL], dd2[NL];
                #pragma unroll
                for (int j = 0; j < NL; ++j) {
                    const v2f It  = Iez[j] * v2exp2(ZL2 * (pref + cl_[j]));
                    const v2f aIt = pa * It;
                    const v2f Gg  = ETA * aIt * v2rsq(ETA * ETA + aIt * aIt);
                    const v2f dN  = KAP + vN[j];
                    const v2f dA  = KAP + vA[j];
                    const v2f ir  = v2rcp(dN * dA);
                    const v2f fN  = vN[j] * dA * ir;
                    const v2f fA  = vA[j] * dN * ir;
                    const v2f eP  = v2exp2(PL2 * vA[j]);
                    const v2f GP  = Gg * vP[j];
                    const v2f bN = MU * vA[j] - GP * eP * fN;
                    const v2f bA = pvar * vD[j] + pGam * vZ[j] - GP * fA - MU * vA[j];
                    const v2f bP = GP * (eP * fN + fA) - grz[j] - pXi * vP[j];
                    dd0[j] = vN[j] + DT * bN;
                    dd1[j] = vA[j] + DT * bA;
                    dd2[j] = vP[j] + DT * bP;
                }

                // ---- WENO3-Z sediment flux on XD ----
                v2f q[NL];
                #pragma unroll
                for (int j = 0; j < NL; ++j) q[j] = XD[j] * dzT[j];
                const v2f qm1 = nbr_m1(q[3]);
                const v2f qm2 = nbr_m1(q[2]);
                const v2f dq0 = q[0] - qm1;
                const v2f dq1 = q[1] - q[0];
                const v2f dq2 = q[2] - q[1];
                const v2f dq3 = q[3] - q[2];
                const v2f s0 = dq0 * dq0, s1 = dq1 * dq1, s2 = dq2 * dq2, s3 = dq3 * dq3;
                const v2f s4 = nbr_p1(s0);
                const v2f sm = nbr_m1(s3);
                const v2f qn0 = q[3] + nbr_p1(dq0);   // q[0] of lane+1
                const v2f f0 = (lane == 0) ? v2s(0.f)    : weno3z_v(qm2, qm1, q[0], sm, s0) * swN[0];
                const v2f f1 = (lane == 0) ? sedc * XD[0] : weno3z_v(qm1, q[0], q[1], s0, s1) * swN[1];
                const v2f f2 = weno3z_v(q[0], q[1], q[2], s1, s2) * swN[2];
                const v2f f3 = weno3z_v(q[1], q[2], q[3], s2, s3) * swN[3];
                const v2f f4 = (lane == ACTL - 1) ? sedc * XD[3]
                                                  : weno3z_v(q[2], q[3], qn0, s3, s4) * swN4;
                const v2f fs[NL + 1] = { f0, f1, f2, f3, f4 };
                #pragma unroll
                for (int j = 0; j < NL; ++j)
                    vD[j] = XD[j] + (fs[j] - fs[j + 1]) * DTdz[j];

                // ---- remaining solves + commit ----
                v2f XZ[NL], X0[NL], X1[NL], X2[NL];
                solve(ddZ, XZ);
                solve(dd0, X0);
                solve(dd1, X1);
                solve(dd2, X2);
                #pragma unroll
                for (int j = 0; j < NL; ++j) {
                    vZ[j] = XZ[j];
                    vN[j] = X0[j] + (pbet - X0[j]) * rap;
                    vA[j] = X1[j];
                    vP[j] = X2[j];
                }

                if (k4 == 1 && k2 == 3 && act) {     // end of day: frame d8+1
                    const size_t fo = (size_t)(d8 + 1) * (5 * NZD);
                    const size_t b0 = ob0base + fo;
                    const size_t b1 = ob1base + fo;
                    WRFRAME(b0, x)
                    WRFRAME(b1, y)
                }
            }
        }
        if (d8 < 4) { curI0 = nxtI0; curSw = nxtSw; }
    }
    #undef WRFRAME
}

extern "C" void kernel_launch(void* const* d_in, const int* in_sizes, int n_in,
                              void* d_out, int out_size, void* d_ws, size_t ws_size,
                              hipStream_t stream) {
    const float* Kz    = (const float*)d_in[0];
    const float* I0    = (const float*)d_in[1];
    const float* alpha = (const float*)d_in[2];
    const float* Xi    = (const float*)d_in[3];
    const float* rho   = (const float*)d_in[4];
    const float* gam   = (const float*)d_in[5];
    const float* Gam   = (const float*)d_in[6];
    const float* varp  = (const float*)d_in[7];
    const float* omg   = (const float*)d_in[8];
    const float* bet   = (const float*)d_in[9];
    const float* N0    = (const float*)d_in[10];
    const float* A0    = (const float*)d_in[11];
    const float* P0    = (const float*)d_in[12];
    const float* Z0    = (const float*)d_in[13];
    const float* Dd0   = (const float*)d_in[14];
    const float* sbw   = (const float*)d_in[15];
    const float* zTp   = (const float*)d_in[16];
    const float* zwp   = (const float*)d_in[17];
    float* out = (float*)d_out;

    dim3 grid(NSC * NWN / 2);   // 384 waves, 2 packed columns each
    dim3 block(64);
    hipLaunchKernelGGL(nnpzd_wave, grid, block, 0, stream,
                       Kz, I0, alpha, Xi, rho, gam, Gam, varp, omg, bet,
                       N0, A0, P0, Z0, Dd0, sbw, zTp, zwp, out);
}

// Round 13
// 55.592 us; speedup vs baseline: 1.2145x; 1.2145x over previous
//
#include <hip/hip_runtime.h>

#define NSC 64      // Ns
#define NWN 12      // nw
#define LWN 6       // lw
#define NZD 200     // Nz
#define NFRAMES 6
#define NL 4        // cells per lane
#define ACTL 50     // active lanes (50*4 = 200)

__device__ __forceinline__ float frcp(float x) { return __builtin_amdgcn_rcpf(x); }
__device__ __forceinline__ float frsq(float x) { return __builtin_amdgcn_rsqf(x); }
#if __has_builtin(__builtin_amdgcn_exp2f)
__device__ __forceinline__ float fexp2(float x) { return __builtin_amdgcn_exp2f(x); }
#else
__device__ __forceinline__ float fexp2(float x) { return exp2f(x); }
#endif

// DPP lane-shift moves (bound_ctrl -> 0 at edges).
// wave_shr1 (0x138): lane i reads lane i-1 ; wave_shl1 (0x130): lane i reads lane i+1
template<int CTRL>
__device__ __forceinline__ float dppmov(float x) {
    return __int_as_float(__builtin_amdgcn_update_dpp(0, __float_as_int(x), CTRL, 0xf, 0xf, true));
}
__device__ __forceinline__ float nbr_p1(float x) { return dppmov<0x130>(x); }  // from lane+1
__device__ __forceinline__ float nbr_m1(float x) { return dppmov<0x138>(x); }  // from lane-1
__device__ __forceinline__ float nbr_p2(float x) { return nbr_p1(nbr_p1(x)); }
__device__ __forceinline__ float nbr_m2(float x) { return nbr_m1(nbr_m1(x)); }

template<int CTRL, int RMASK, bool BC>
__device__ __forceinline__ float dppadd(float x) {
    const int t = __builtin_amdgcn_update_dpp(0, __float_as_int(x), CTRL, RMASK, 0xf, BC);
    return x + __int_as_float(t);
}
// wave64 inclusive scan, 6 VALU-DPP ops
__device__ __forceinline__ float wave_iscan(float x) {
    x = dppadd<0x111, 0xf, true>(x);
    x = dppadd<0x112, 0xf, true>(x);
    x = dppadd<0x114, 0xf, true>(x);
    x = dppadd<0x118, 0xf, true>(x);
    x = dppadd<0x142, 0xa, false>(x);
    x = dppadd<0x143, 0xc, false>(x);
    return x;
}

// WENO3-Z with precomputed smoothness b1,b2 and single reciprocal.
__device__ __forceinline__ float weno3z_b(float qm, float q0, float qp, float b1, float b2) {
    const float qi1 = 1.5f * q0 - 0.5f * qm;
    const float qi2 = 0.5f * (q0 + qp);
    const float b1e = b1 + 1e-14f;
    const float b2e = b2 + 1e-14f;
    const float tau = fabsf(b2 - b1);
    const float W1 = (b1e + tau) * b2e;
    const float W2 = 2.f * (b2e + tau) * b1e;
    return (W1 * qi1 + W2 * qi2) * frcp(W1 + W2);
}

__global__ __launch_bounds__(64, 1) void nnpzd_wave(
    const float* __restrict__ Kz, const float* __restrict__ I0,
    const float* __restrict__ alpha_p, const float* __restrict__ Xi_p,
    const float* __restrict__ rho_p, const float* __restrict__ gamma_p,
    const float* __restrict__ Gamma_p, const float* __restrict__ varphi_p,
    const float* __restrict__ omega_p, const float* __restrict__ beta_p,
    const float* __restrict__ NO3_0, const float* __restrict__ NH4_0,
    const float* __restrict__ P_0, const float* __restrict__ Z_0,
    const float* __restrict__ D_0, const float* __restrict__ subw,
    const float* __restrict__ zT, const float* __restrict__ zw,
    float* __restrict__ out)
{
    const float XI = 0.067f, ZETA = 0.0095f, LAM = 0.06f, PSI = 1.46f;
    const float MU = 0.25f, ETA = 1.5f, KAP = 1.0f, DT = 0.125f;
    const float LOG2E = 1.44269504088896340736f;
    const float ZL2 = -ZETA * LOG2E;
    const float PL2 = -PSI * LOG2E;
    const float LL2 = -LAM * LOG2E;

    const int col  = blockIdx.x;            // one column per wave
    const int si   = col / NWN;
    const int wi   = col - si * NWN;
    const int lane = threadIdx.x;
    const bool act = lane < ACTL;
    const int  c0  = lane * NL;

    const float pa   = alpha_p[si];
    const float pXi  = Xi_p[si];
    const float prho = rho_p[si];
    const float pgam = gamma_p[si];
    const float pGam = Gamma_p[si];
    const float pvar = varphi_p[si];
    const float sedc = omega_p[si];
    const float pbet = beta_p[si];
    const int   sw0  = (int)subw[wi * LWN];

    // ---- per-lane constant geometry ----
    float dzT[NL], DTdz[NL], ezT[NL], kAf[NL], kCf[NL], swN[NL], swN4;
    {
        float dzw_[NL + 2];
        #pragma unroll
        for (int j = 0; j <= NL + 1; ++j) {
            const int i = act ? (c0 + j) : 0;
            dzw_[j] = (i == 0)   ? 0.5f * (zw[1] - zw[0])
                    : (i >= NZD) ? 0.5f * (zw[NZD] - zw[NZD - 1])
                                 : (zT[i] - zT[i - 1]);
        }
        #pragma unroll
        for (int j = 0; j < NL; ++j) {
            const int i = act ? (c0 + j) : 0;
            const float dz = zw[i + 1] - zw[i];
            dzT[j]  = dz;
            DTdz[j] = act ? (DT / dz) : 0.f;
            ezT[j]  = expf(-XI * zT[i]);
            kAf[j]  = (act && (c0 + j) >= 1)       ? (-DT / (dz * dzw_[j]))     : 0.f;
            kCf[j]  = (act && (c0 + j) <= NZD - 2) ? (-DT / (dz * dzw_[j + 1])) : 0.f;
            swN[j]  = act ? (sedc / dzw_[j]) : 0.f;
        }
        swN4 = act ? (sedc / dzw_[NL]) : 0.f;
    }

    // ---- initial state (float4 loads) ----
    float vN[NL], vA[NL], vP[NL], vZ[NL], vD[NL];
    {
        const size_t ib = (size_t)col * NZD + c0;
        if (act) {
            const float4 n4 = *reinterpret_cast<const float4*>(&NO3_0[ib]);
            const float4 a4 = *reinterpret_cast<const float4*>(&NH4_0[ib]);
            const float4 p4 = *reinterpret_cast<const float4*>(&P_0[ib]);
            const float4 z4 = *reinterpret_cast<const float4*>(&Z_0[ib]);
            const float4 d4 = *reinterpret_cast<const float4*>(&D_0[ib]);
            vN[0]=n4.x; vN[1]=n4.y; vN[2]=n4.z; vN[3]=n4.w;
            vA[0]=a4.x; vA[1]=a4.y; vA[2]=a4.z; vA[3]=a4.w;
            vP[0]=p4.x; vP[1]=p4.y; vP[2]=p4.z; vP[3]=p4.w;
            vZ[0]=z4.x; vZ[1]=z4.y; vZ[2]=z4.z; vZ[3]=z4.w;
            vD[0]=d4.x; vD[1]=d4.y; vD[2]=d4.z; vD[3]=d4.w;
        } else {
            #pragma unroll
            for (int j = 0; j < NL; ++j) { vN[j]=vA[j]=vP[j]=vZ[j]=vD[j]=0.f; }
        }
    }

    // frame 0
    const size_t obase = (size_t)col * (NFRAMES * 5 * NZD);
    if (act) {
        *reinterpret_cast<float4*>(&out[obase + 0 * NZD + c0]) = make_float4(vN[0],vN[1],vN[2],vN[3]);
        *reinterpret_cast<float4*>(&out[obase + 1 * NZD + c0]) = make_float4(vA[0],vA[1],vA[2],vA[3]);
        *reinterpret_cast<float4*>(&out[obase + 2 * NZD + c0]) = make_float4(vP[0],vP[1],vP[2],vP[3]);
        *reinterpret_cast<float4*>(&out[obase + 3 * NZD + c0]) = make_float4(vZ[0],vZ[1],vZ[2],vZ[3]);
        *reinterpret_cast<float4*>(&out[obase + 4 * NZD + c0]) = make_float4(vD[0],vD[1],vD[2],vD[3]);
    }

    const float* KzBase = Kz + (size_t)si * (2 * NWN * LWN + 2) * (NZD + 1);
    const float* I0row  = I0 + (size_t)si * (NWN * LWN + 1);

    // ---- factors rebuilt every 4 steps ----
    float t00, t10, t11, t20, t21, t22, t30, t31, t32, t33;
    float ecf0, ecf1, ecf2;
    float aa0, aa1, aa2, cl0, cl1, cl2, cl3;
    float E1a, E2a, ivF, E1bF, E2bF;       // round-1; round-2 factors pre-folded with invbF
    float Iez[NL];

    // prefetch first Kz row
    float kzc[NL + 1];
    {
        const float* kzp = KzBase + (size_t)(2 * sw0) * (NZD + 1);
        #pragma unroll
        for (int j = 0; j <= NL; ++j) kzc[j] = act ? kzp[c0 + j] : 0.f;
    }
    float curI0 = I0row[sw0];
    float curSw = subw[wi * LWN + 1];
    float nxtI0 = 0.f, nxtSw = 0.f;

    // per-tracer implicit solve (DPP-only cross-lane; 2 PCR rounds, folded final scale)
    auto solve = [&](const float* d, float* Xo) {
        const float Ec  = ecf0 * d[0] + ecf1 * d[1] + ecf2 * d[2];
        const float En  = nbr_p1(Ec);
        const float Dt3 = t30 * d[0] + t31 * d[1] + t32 * d[2] + t33 * d[3];
        float dR = Dt3 - cl3 * En;
        dR += E1a * nbr_m1(dR) + E2a * nbr_p1(dR);
        const float y  = ivF * dR + E1bF * nbr_m2(dR) + E2bF * nbr_p2(dR);
        const float xm = nbr_m1(y);
        const float Dt0 = t00 * d[0];
        const float Dt1 = t10 * d[0] + t11 * d[1];
        const float Dt2 = t20 * d[0] + t21 * d[1] + t22 * d[2];
        Xo[3] = y;
        Xo[2] = Dt2 - aa2 * xm - cl2 * Xo[3];
        Xo[1] = Dt1 - aa1 * xm - cl1 * Xo[2];
        Xo[0] = Dt0 - aa0 * xm - cl0 * Xo[1];
    };

    for (int d8 = 0; d8 < 5; ++d8) {
        if (d8 < 4) {
            nxtI0 = I0row[sw0 + d8 + 1];
            nxtSw = subw[wi * LWN + d8 + 2];
        }
        #pragma unroll
        for (int j = 0; j < NL; ++j) Iez[j] = curI0 * ezT[j];
        const float rap = 0.05f * (fminf(fmaxf(curSw - 30.f, 0.f), 1.f)
                                 - fminf(fmaxf(curSw - 60.f, 0.f), 1.f));

        for (int k4 = 0; k4 < 2; ++k4) {
            // ---- rebuild matrix factors from prefetched Kz ----
            float ac_[NL], cc_[NL];
            #pragma unroll
            for (int j = 0; j < NL; ++j) {
                ac_[j] = kAf[j] * kzc[j];
                cc_[j] = kCf[j] * kzc[j + 1];
            }
            {   // prefetch next Kz row (row = 2*sw0 + 2*d8 + k4 + 1, always in-bounds)
                const float* kzp = KzBase + (size_t)(2 * sw0 + 2 * d8 + k4 + 1) * (NZD + 1);
                #pragma unroll
                for (int j = 0; j <= NL; ++j) kzc[j] = act ? kzp[c0 + j] : 0.f;
            }
            const float iv0 = frcp(1.f - ac_[0] - cc_[0]);
            cl0 = cc_[0] * iv0;
            aa0 = ac_[0] * iv0;
            t00 = iv0;
            const float iv1 = frcp(1.f - ac_[1] - cc_[1] - ac_[1] * cl0);
            const float qf1 = ac_[1] * iv1;
            cl1 = cc_[1] * iv1;
            aa1 = -qf1 * aa0;
            t11 = iv1; t10 = -qf1 * t00;
            const float iv2 = frcp(1.f - ac_[2] - cc_[2] - ac_[2] * cl1);
            const float qf2 = ac_[2] * iv2;
            cl2 = cc_[2] * iv2;
            aa2 = -qf2 * aa1;
            t22 = iv2; t21 = -qf2 * t11; t20 = -qf2 * t10;
            const float iv3 = frcp(1.f - ac_[3] - cc_[3] - ac_[3] * cl2);
            const float qf3 = ac_[3] * iv3;
            cl3 = cc_[3] * iv3;
            const float aa3 = -qf3 * aa2;
            t33 = iv3; t32 = -qf3 * t22; t31 = -qf3 * t21; t30 = -qf3 * t20;
            const float c01 = cl0 * cl1;
            ecf0 = t00 - cl0 * t10 + c01 * t20;
            ecf1 = -cl0 * t11 + c01 * t21;
            ecf2 = c01 * t22;
            const float F = aa0 - cl0 * (aa1 - cl1 * aa2);
            const float G = cl0 * cl1 * cl2;
            const float Fn = nbr_p1(F);
            const float Gn = nbr_p1(G);
            float aR = aa3;
            float bR = 1.f - cl3 * Fn;
            float cR = -cl3 * Gn;
            if (!act) { aR = 0.f; bR = 1.f; cR = 0.f; }
            // PCR round 1 (offset 1)
            const float ib  = frcp(bR);
            const float am  = nbr_m1(aR), ibm = nbr_m1(ib), cm = nbr_m1(cR);
            const float ap  = nbr_p1(aR), ibp = nbr_p1(ib), cp = nbr_p1(cR);
            E1a = -aR * ibm;
            E2a = -cR * ibp;
            const float b1r = bR + E1a * cm + E2a * ap;
            const float a1r = E1a * am;
            const float c1r = E2a * cp;
            // PCR round 2 (offset 2), final reciprocal folded into factors
            const float ib1  = frcp(b1r);
            const float am2  = nbr_m2(a1r), ib1m = nbr_m2(ib1), cm2 = nbr_m2(c1r);
            const float ap2  = nbr_p2(a1r), ib1p = nbr_p2(ib1), cp2 = nbr_p2(c1r);
            const float E1b = -a1r * ib1m;
            const float E2b = -c1r * ib1p;
            const float invbF = frcp(b1r + E1b * cm2 + E2b * ap2);
            ivF  = invbF;
            E1bF = E1b * invbF;
            E2bF = E2b * invbF;

            #pragma unroll
            for (int k2 = 0; k2 < 4; ++k2) {
                // ---- cumsum of P*dzT ----
                float cl_[NL];
                float run = 0.f;
                #pragma unroll
                for (int j = 0; j < NL; ++j) { run += vP[j] * dzT[j]; cl_[j] = run; }
                const float pref = wave_iscan(run) - run;

                // ---- It-independent tendencies (Z, D) ----
                float grz[NL], ddZ[NL], ddD[NL];
                #pragma unroll
                for (int j = 0; j < NL; ++j) {
                    grz[j] = prho * (1.f - fexp2(LL2 * vP[j])) * vZ[j];
                    ddZ[j] = vZ[j] + DT * ((1.f - pgam) * grz[j] - pGam * vZ[j]);
                    ddD[j] = vD[j] + DT * (pgam * grz[j] + pXi * vP[j] - pvar * vD[j]);
                }
                float XD[NL];
                solve(ddD, XD);        // D first: feeds the long WENO chain

                // ---- It-dependent tendencies ----
                float dd0[NL], dd1[NL], dd2[NL];
                #pragma unroll
                for (int j = 0; j < NL; ++j) {
                    const float It  = Iez[j] * fexp2(ZL2 * (pref + cl_[j]));
                    const float aIt = pa * It;
                    const float Gg  = ETA * aIt * frsq(ETA * ETA + aIt * aIt);
                    const float dN  = KAP + vN[j];
                    const float dA  = KAP + vA[j];
                    const float ir  = frcp(dN * dA);
                    const float fN  = vN[j] * dA * ir;
                    const float fA  = vA[j] * dN * ir;
                    const float eP  = fexp2(PL2 * vA[j]);
                    const float GP  = Gg * vP[j];
                    const float bN = MU * vA[j] - GP * eP * fN;
                    const float bA = pvar * vD[j] + pGam * vZ[j] - GP * fA - MU * vA[j];
                    const float bP = GP * (eP * fN + fA) - grz[j] - pXi * vP[j];
                    dd0[j] = vN[j] + DT * bN;
                    dd1[j] = vA[j] + DT * bA;
                    dd2[j] = vP[j] + DT * bP;
                }

                // ---- WENO3-Z sediment flux on XD (full f0 evaluation, as in R8) ----
                float q[NL];
                #pragma unroll
                for (int j = 0; j < NL; ++j) q[j] = XD[j] * dzT[j];
                const float qm1 = nbr_m1(q[3]);
                const float qm2 = nbr_m1(q[2]);
                const float dq0 = q[0] - qm1;
                const float dq1 = q[1] - q[0];
                const float dq2 = q[2] - q[1];
                const float dq3 = q[3] - q[2];
                const float s0 = dq0 * dq0, s1 = dq1 * dq1, s2 = dq2 * dq2, s3 = dq3 * dq3;
                const float s4 = nbr_p1(s0);
                const float sm = nbr_m1(s3);
                const float qn0 = q[3] + nbr_p1(dq0);   // q[0] of lane+1
                const float f0 = (lane == 0) ? 0.f           : weno3z_b(qm2, qm1, q[0], sm, s0) * swN[0];
                const float f1 = (lane == 0) ? sedc * XD[0]  : weno3z_b(qm1, q[0], q[1], s0, s1) * swN[1];
                const float f2 = weno3z_b(q[0], q[1], q[2], s1, s2) * swN[2];
                const float f3 = weno3z_b(q[1], q[2], q[3], s2, s3) * swN[3];
                const float f4 = (lane == ACTL - 1) ? sedc * XD[3]
                                                    : weno3z_b(q[2], q[3], qn0, s3, s4) * swN4;
                const float fs[NL + 1] = { f0, f1, f2, f3, f4 };
                #pragma unroll
                for (int j = 0; j < NL; ++j)
                    vD[j] = XD[j] + (fs[j] - fs[j + 1]) * DTdz[j];

                // ---- remaining solves + commit ----
                float XZ[NL], X0[NL], X1[NL], X2[NL];
                solve(ddZ, XZ);
                solve(dd0, X0);
                solve(dd1, X1);
                solve(dd2, X2);
                #pragma unroll
                for (int j = 0; j < NL; ++j) {
                    vZ[j] = XZ[j];
                    vN[j] = X0[j] + (pbet - X0[j]) * rap;
                    vA[j] = X1[j];
                    vP[j] = X2[j];
                }

                if (k4 == 1 && k2 == 3 && act) {     // end of day: frame d8+1
                    const size_t ob = obase + (size_t)(d8 + 1) * (5 * NZD) + c0;
                    *reinterpret_cast<float4*>(&out[ob + 0 * NZD]) = make_float4(vN[0],vN[1],vN[2],vN[3]);
                    *reinterpret_cast<float4*>(&out[ob + 1 * NZD]) = make_float4(vA[0],vA[1],vA[2],vA[3]);
                    *reinterpret_cast<float4*>(&out[ob + 2 * NZD]) = make_float4(vP[0],vP[1],vP[2],vP[3]);
                    *reinterpret_cast<float4*>(&out[ob + 3 * NZD]) = make_float4(vZ[0],vZ[1],vZ[2],vZ[3]);
                    *reinterpret_cast<float4*>(&out[ob + 4 * NZD]) = make_float4(vD[0],vD[1],vD[2],vD[3]);
                }
            }
        }
        if (d8 < 4) { curI0 = nxtI0; curSw = nxtSw; }
    }
}

extern "C" void kernel_launch(void* const* d_in, const int* in_sizes, int n_in,
                              void* d_out, int out_size, void* d_ws, size_t ws_size,
                              hipStream_t stream) {
    const float* Kz    = (const float*)d_in[0];
    const float* I0    = (const float*)d_in[1];
    const float* alpha = (const float*)d_in[2];
    const float* Xi    = (const float*)d_in[3];
    const float* rho   = (const float*)d_in[4];
    const float* gam   = (const float*)d_in[5];
    const float* Gam   = (const float*)d_in[6];
    const float* varp  = (const float*)d_in[7];
    const float* omg   = (const float*)d_in[8];
    const float* bet   = (const float*)d_in[9];
    const float* N0    = (const float*)d_in[10];
    const float* A0    = (const float*)d_in[11];
    const float* P0    = (const float*)d_in[12];
    const float* Z0    = (const float*)d_in[13];
    const float* Dd0   = (const float*)d_in[14];
    const float* sbw   = (const float*)d_in[15];
    const float* zTp   = (const float*)d_in[16];
    const float* zwp   = (const float*)d_in[17];
    float* out = (float*)d_out;

    dim3 grid(NSC * NWN);   // 768 waves, 1 column each
    dim3 block(64);
    hipLaunchKernelGGL(nnpzd_wave, grid, block, 0, stream,
                       Kz, I0, alpha, Xi, rho, gam, Gam, varp, omg, bet,
                       N0, A0, P0, Z0, Dd0, sbw, zTp, zwp, out);
}